// Round 6
// baseline (100.691 us; speedup 1.0000x reference)
//
#include <hip/hip_runtime.h>

#define HW 4096      // 64*64 pixels per image
#define NC 256       // C_in
#define ND 256       // C_out
#define NB 16        // batch

typedef _Float16 half4_t __attribute__((ext_vector_type(4)));
typedef _Float16 half8_t __attribute__((ext_vector_type(8)));
typedef float floatx2 __attribute__((ext_vector_type(2)));
typedef float floatx4 __attribute__((ext_vector_type(4)));

#define MSCALE 64.0f                 // M scaled by 2^6 -> P,y scaled by 2^12
#define INV_MSCALE2 (1.0f / 4096.0f)
#define EPS_SCALED (1e-5f * 4096.0f * 4096.0f)   // eps for scaled-y stats

// ---------------------------------------------------------------------------
// prep: pack A-operand fragment streams, K-chunk-major:
//   addr = ((ks*16 + rt)*64 + l)*8 + j
// Also zeroes ssum/ssq (replaces a memset launch).
// ---------------------------------------------------------------------------
__global__ __launch_bounds__(256) void prep_weights(
        const float* __restrict__ w_core, const float* __restrict__ w_out,
        _Float16* __restrict__ W1p, _Float16* __restrict__ W2p,
        float* __restrict__ ssum) {
    int tid = blockIdx.x * 256 + threadIdx.x;   // 16384 threads
    if (tid < 8192) ssum[tid] = 0.f;            // ssum+ssq contiguous
    int l   = tid & 63;
    int rt  = (tid >> 6) & 15;
    int ks  = (tid >> 10) & 7;
    int sel = tid >> 13;
    int row = l & 15, kg = l >> 4;
    half8_t v;
    if (sel == 0) {
        int r = rt, k = row;
#pragma unroll
        for (int j = 0; j < 8; ++j) {
            int c = ks * 32 + kg * 8 + j;
            v[j] = (_Float16)(w_core[r * 4096 + c * 16 + k] * MSCALE);
        }
        *(half8_t*)&W1p[(size_t)((ks * 16 + rt) * 64 + l) * 8] = v;
    } else {
        int d = rt * 16 + row;
#pragma unroll
        for (int j = 0; j < 8; ++j) {
            int eg = ks * 32 + kg * 8 + j, e = eg >> 4, g = eg & 15;
            v[j] = (_Float16)w_out[g * 4096 + d * 16 + e];
        }
        *(half8_t*)&W2p[(size_t)((ks * 16 + rt) * 64 + l) * 8] = v;
    }
}

// ---------------------------------------------------------------------------
// Fused: M = W1T.x -> P = M*M -> yT = W2T.P, + partial instance-norm stats.
// 32 px/block, 4 waves; wave owns rt/dt {4w..4w+3} x 2 pixel tiles.
// LDS 32KB/block -> 4 blocks/CU (16 waves, 50% occ ceiling).
// Weight fragments software-pipelined in registers (1-deep rolling prefetch).
// ---------------------------------------------------------------------------
template<bool F16Y>
__global__ __launch_bounds__(256, 4) void compute_y(
        const float* __restrict__ x, const _Float16* __restrict__ W1p,
        const _Float16* __restrict__ W2p, float* __restrict__ y,
        _Float16* __restrict__ y16, float* __restrict__ ssum,
        float* __restrict__ ssq) {
    __shared__ __align__(16) _Float16 R1[8192];   // 16KB: XT -> PL
    __shared__ __align__(16) _Float16 R2[8192];   // 16KB: MT

    const int t = threadIdx.x;
    const int l = t & 63, w = t >> 6;
    const int a = blockIdx.x >> 7;
    const int pixbase = (blockIdx.x & 127) * 32;
    const int row16 = l & 15, kg = l >> 4;
    const float* xa = x + (size_t)a * NC * HW + pixbase;

    // ---- cooperative x load -> XT[px][c] f16 (16B-unit XOR swizzle) ----
    {
        const int px = t & 31;
        const int o0 = t >> 5;                    // 0..7
#pragma unroll
        for (int q = 0; q < 4; ++q) {
            const int oct = q * 8 + o0;           // 0..31
            half8_t hv;
#pragma unroll
            for (int j = 0; j < 8; ++j)
                hv[j] = (_Float16)xa[(size_t)(oct * 8 + j) * HW + px];
            *(half8_t*)&R1[px * 256 + ((oct ^ (px & 15)) << 3)] = hv;
        }
    }
    __syncthreads();                                    // (1)

    // ---- stage A: MT = W1T . x  (rolling weight prefetch) ----
    floatx4 acc[4][2];
#pragma unroll
    for (int i = 0; i < 4; ++i)
#pragma unroll
        for (int j = 0; j < 2; ++j) acc[i][j] = (floatx4){0.f, 0.f, 0.f, 0.f};
    {
        const half8_t* W1v = (const half8_t*)W1p;
        half8_t af[4], afn[4];
#pragma unroll
        for (int rq = 0; rq < 4; ++rq) af[rq] = W1v[(w * 4 + rq) * 64 + l];
        for (int ks = 0; ks < 8; ++ks) {
            if (ks < 7) {
#pragma unroll
                for (int rq = 0; rq < 4; ++rq)
                    afn[rq] = W1v[((ks + 1) * 16 + w * 4 + rq) * 64 + l];
            }
#pragma unroll
            for (int pt = 0; pt < 2; ++pt) {
                const int px = pt * 16 + row16;
                half8_t bf = *(const half8_t*)
                    &R1[px * 256 + (((ks * 4 + kg) ^ row16) << 3)];
#pragma unroll
                for (int rq = 0; rq < 4; ++rq)
                    acc[rq][pt] = __builtin_amdgcn_mfma_f32_16x16x32_f16(
                                      af[rq], bf, acc[rq][pt], 0, 0, 0);
            }
#pragma unroll
            for (int rq = 0; rq < 4; ++rq) af[rq] = afn[rq];
        }
    }
    // MT write: D col=px(l&15), row rk = rt*16 + kg*4 + r2 (half4 units)
#pragma unroll
    for (int rq = 0; rq < 4; ++rq) {
        const int rk4 = (w * 4 + rq) * 4 + kg;
#pragma unroll
        for (int pt = 0; pt < 2; ++pt) {
            const int px = pt * 16 + row16;
            half4_t hv;
#pragma unroll
            for (int r2 = 0; r2 < 4; ++r2) hv[r2] = (_Float16)acc[rq][pt][r2];
            *(half4_t*)&R2[px * 256 + ((rk4 ^ row16) << 2)] = hv;
        }
    }
    __syncthreads();                                    // (2)

    // ---- prefetch stage-C ks=0 weight fragments (fly under stage B) ----
    const half8_t* W2v = (const half8_t*)W2p;
    half8_t caf[4], cafn[4];
#pragma unroll
    for (int dq = 0; dq < 4; ++dq) caf[dq] = W2v[(w * 4 + dq) * 64 + l];

    // ---- stage B: per-pixel P = M*M (8 threads/pixel, e = i*8+qe) ----
    {
        const int p = t >> 3, qe = t & 7, ps = p & 15;
        const _Float16* Mp = &R2[p * 256];
        float Af[2][16];
#pragma unroll
        for (int i = 0; i < 2; ++i) {
            const int e = i * 8 + qe;
#pragma unroll
            for (int f4 = 0; f4 < 4; ++f4) {
                half4_t v = *(const half4_t*)
                    &Mp[(((e * 4 + f4) ^ ps) << 2)];
#pragma unroll
                for (int j = 0; j < 4; ++j) Af[i][f4 * 4 + j] = (float)v[j];
            }
        }
        floatx2 Pacc[2][8];
#pragma unroll
        for (int i = 0; i < 2; ++i)
#pragma unroll
            for (int g2 = 0; g2 < 8; ++g2) Pacc[i][g2] = (floatx2){0.f, 0.f};
#pragma unroll
        for (int f = 0; f < 16; ++f) {
            floatx2 Bg[8];
#pragma unroll
            for (int g4 = 0; g4 < 4; ++g4) {
                half4_t v = *(const half4_t*)
                    &Mp[(((f * 4 + g4) ^ ps) << 2)];   // broadcast across qe
                Bg[g4 * 2]     = (floatx2){(float)v[0], (float)v[1]};
                Bg[g4 * 2 + 1] = (floatx2){(float)v[2], (float)v[3]};
            }
#pragma unroll
            for (int i = 0; i < 2; ++i) {
                floatx2 a2 = {Af[i][f], Af[i][f]};
#pragma unroll
                for (int g2 = 0; g2 < 8; ++g2)
                    Pacc[i][g2] = __builtin_elementwise_fma(a2, Bg[g2], Pacc[i][g2]);
            }
        }
        // PL[px][eg] f16 (half8 units) into R1 (XT dead)
#pragma unroll
        for (int i = 0; i < 2; ++i) {
            const int e = i * 8 + qe;
#pragma unroll
            for (int h2 = 0; h2 < 2; ++h2) {
                half8_t hv;
#pragma unroll
                for (int j = 0; j < 8; ++j)
                    hv[j] = (_Float16)Pacc[i][h2 * 4 + (j >> 1)][j & 1];
                *(half8_t*)&R1[p * 256 + (((e * 2 + h2) ^ ps) << 3)] = hv;
            }
        }
    }
    __syncthreads();                                    // (3)

    // ---- stage C: yT = W2T . P  (rolling weight prefetch) ----
    floatx4 cacc[4][2];
#pragma unroll
    for (int i = 0; i < 4; ++i)
#pragma unroll
        for (int j = 0; j < 2; ++j) cacc[i][j] = (floatx4){0.f, 0.f, 0.f, 0.f};
    for (int ks = 0; ks < 8; ++ks) {
        if (ks < 7) {
#pragma unroll
            for (int dq = 0; dq < 4; ++dq)
                cafn[dq] = W2v[((ks + 1) * 16 + w * 4 + dq) * 64 + l];
        }
#pragma unroll
        for (int pt = 0; pt < 2; ++pt) {
            const int px = pt * 16 + row16;
            half8_t bf = *(const half8_t*)
                &R1[px * 256 + (((ks * 4 + kg) ^ row16) << 3)];
#pragma unroll
            for (int dq = 0; dq < 4; ++dq)
                cacc[dq][pt] = __builtin_amdgcn_mfma_f32_16x16x32_f16(
                                   caf[dq], bf, cacc[dq][pt], 0, 0, 0);
        }
#pragma unroll
        for (int dq = 0; dq < 4; ++dq) caf[dq] = cafn[dq];
    }

    // ---- epilogue: stores (f16 scaled or f32) + shuffle-reduced stats ----
    float*     ya   = y   + (size_t)a * ND * HW + pixbase;
    _Float16*  ya16 = F16Y ? (y16 + (size_t)a * ND * HW + pixbase) : nullptr;
#pragma unroll
    for (int dq = 0; dq < 4; ++dq) {
        const int dbase = (w * 4 + dq) * 16 + kg * 4;
#pragma unroll
        for (int r2 = 0; r2 < 4; ++r2) {
            const int d = dbase + r2;
            float s = 0.f, q2 = 0.f;
#pragma unroll
            for (int pt = 0; pt < 2; ++pt) {
                float v;
                if (F16Y) {
                    _Float16 hv = (_Float16)cacc[dq][pt][r2];   // ys = 4096*y
                    ya16[(size_t)d * HW + pt * 16 + row16] = hv;
                    v = (float)hv;
                } else {
                    v = cacc[dq][pt][r2] * INV_MSCALE2;
                    ya[(size_t)d * HW + pt * 16 + row16] = v;
                }
                s += v; q2 += v * v;
            }
#pragma unroll
            for (int off = 1; off < 16; off <<= 1) {
                s  += __shfl_xor(s, off);
                q2 += __shfl_xor(q2, off);
            }
            if (row16 == 0) {
                atomicAdd(&ssum[a * 256 + d], s);
                atomicAdd(&ssq [a * 256 + d], q2);
            }
        }
    }
}

// ---------------------------------------------------------------------------
// finalize (f16 path): one block per (a,d); stats computed inline from ssum/ssq
// ---------------------------------------------------------------------------
__global__ __launch_bounds__(256) void finalize_f16(
        const _Float16* __restrict__ y16, const float* __restrict__ ssum,
        const float* __restrict__ ssq, float* __restrict__ out) {
    const int ad = blockIdx.x;
    const float m  = ssum[ad] * (1.f / HW);
    const float sv = ssq[ad] * (1.f / HW) - m * m;
    const float s  = rsqrtf(sv + EPS_SCALED);
    const size_t base = (size_t)ad * HW + threadIdx.x * 16;
    half8_t h0 = *(const half8_t*)&y16[base];
    half8_t h1 = *(const half8_t*)&y16[base + 8];
    float o[16];
#pragma unroll
    for (int j = 0; j < 8; ++j) {
        float z0 = ((float)h0[j] - m) * s;
        float z1 = ((float)h1[j] - m) * s;
        o[j]     = z0 / (1.f + fabsf(z0));
        o[8 + j] = z1 / (1.f + fabsf(z1));
    }
#pragma unroll
    for (int q = 0; q < 4; ++q)
        *(float4*)&out[base + q * 4] =
            make_float4(o[q * 4], o[q * 4 + 1], o[q * 4 + 2], o[q * 4 + 3]);
}

// ---------------------------------------------------------------------------
// finalize (f32 fallback): in-place on d_out, inline stats
// ---------------------------------------------------------------------------
__global__ __launch_bounds__(256) void finalize_f32(
        float* __restrict__ y, const float* __restrict__ ssum,
        const float* __restrict__ ssq) {
    const int i4 = blockIdx.x * 256 + threadIdx.x;
    const int ad = i4 >> 10;
    const float m  = ssum[ad] * (1.f / HW);
    const float sv = ssq[ad] * (1.f / HW) - m * m;
    const float s  = rsqrtf(sv + 1e-5f);
    float4 v = ((const float4*)y)[i4];
    float vv[4] = {v.x, v.y, v.z, v.w};
#pragma unroll
    for (int lq = 0; lq < 4; ++lq) {
        float z = (vv[lq] - m) * s;
        vv[lq] = z / (1.f + fabsf(z));
    }
    ((float4*)y)[i4] = make_float4(vv[0], vv[1], vv[2], vv[3]);
}

// ---------------------------------------------------------------------------
extern "C" void kernel_launch(void* const* d_in, const int* in_sizes, int n_in,
                              void* d_out, int out_size, void* d_ws, size_t ws_size,
                              hipStream_t stream) {
    const float* x      = (const float*)d_in[0];
    const float* w_core = (const float*)d_in[1];
    const float* w_out  = (const float*)d_in[2];
    float* y = (float*)d_out;

    char* wsb = (char*)d_ws;
    _Float16* W1p = (_Float16*)wsb;                       // 128KB
    _Float16* W2p = (_Float16*)(wsb + 131072);            // 128KB
    float* ssum   = (float*)(wsb + 262144);               // 16KB
    float* ssq    = (float*)(wsb + 278528);               // 16KB
    _Float16* y16 = (_Float16*)(wsb + 294912);            // 32MB (f16 path)

    const size_t need_f16 = 294912 + (size_t)NB * ND * HW * sizeof(_Float16);
    const bool use_f16 = ws_size >= need_f16;

    prep_weights<<<64, 256, 0, stream>>>(w_core, w_out, W1p, W2p, ssum);
    if (use_f16) {
        compute_y<true><<<2048, 256, 0, stream>>>(x, W1p, W2p, y, y16, ssum, ssq);
        finalize_f16<<<4096, 256, 0, stream>>>(y16, ssum, ssq, y);
    } else {
        compute_y<false><<<2048, 256, 0, stream>>>(x, W1p, W2p, y, nullptr, ssum, ssq);
        finalize_f32<<<16384, 256, 0, stream>>>(y, ssum, ssq);
    }
}

// Round 8
// 82.497 us; speedup vs baseline: 1.2205x; 1.2205x over previous
//
#include <hip/hip_runtime.h>

#define HW 4096      // 64*64 pixels per image
#define NC 256       // C_in
#define ND 256       // C_out
#define NB 16        // batch

typedef _Float16 half2_t __attribute__((ext_vector_type(2)));
typedef _Float16 half4_t __attribute__((ext_vector_type(4)));
typedef _Float16 half8_t __attribute__((ext_vector_type(8)));
typedef __fp16   fp16x2  __attribute__((ext_vector_type(2)));
typedef float floatx2 __attribute__((ext_vector_type(2)));
typedef float floatx4 __attribute__((ext_vector_type(4)));

#define MSCALE 64.0f                 // M scaled by 2^6 -> P,y scaled by 2^12
#define INV_MSCALE2 (1.0f / 4096.0f)
#define EPS_SCALED (1e-5f * 4096.0f * 4096.0f)   // eps for scaled-y stats

// ---------------------------------------------------------------------------
// prep: pack A-operand fragment streams, K-chunk-major:
//   addr = ((ks*16 + rt)*64 + l)*8 + j
// Also zeroes ssum/ssq (replaces a memset launch).
// ---------------------------------------------------------------------------
__global__ __launch_bounds__(256) void prep_weights(
        const float* __restrict__ w_core, const float* __restrict__ w_out,
        _Float16* __restrict__ W1p, _Float16* __restrict__ W2p,
        float* __restrict__ ssum) {
    int tid = blockIdx.x * 256 + threadIdx.x;   // 16384 threads
    if (tid < 8192) ssum[tid] = 0.f;            // ssum+ssq contiguous
    int l   = tid & 63;
    int rt  = (tid >> 6) & 15;
    int ks  = (tid >> 10) & 7;
    int sel = tid >> 13;
    int row = l & 15, kg = l >> 4;
    half8_t v;
    if (sel == 0) {
        int r = rt, k = row;
#pragma unroll
        for (int j = 0; j < 8; ++j) {
            int c = ks * 32 + kg * 8 + j;
            v[j] = (_Float16)(w_core[r * 4096 + c * 16 + k] * MSCALE);
        }
        *(half8_t*)&W1p[(size_t)((ks * 16 + rt) * 64 + l) * 8] = v;
    } else {
        int d = rt * 16 + row;
#pragma unroll
        for (int j = 0; j < 8; ++j) {
            int eg = ks * 32 + kg * 8 + j, e = eg >> 4, g = eg & 15;
            v[j] = (_Float16)w_out[g * 4096 + d * 16 + e];
        }
        *(half8_t*)&W2p[(size_t)((ks * 16 + rt) * 64 + l) * 8] = v;
    }
}

// ---------------------------------------------------------------------------
// Fused: M = W1T.x -> P = M*M -> yT = W2T.P, + partial instance-norm stats.
// 64 px/block, 4 waves; wave owns rt/dt {4w..4w+3} x all 4 pixel tiles.
// LDS 64KB single region S, phase-reused:
//   phase 0: XT[64px][256c] f16 (first 32KB of S)
//   phase 1: MT[64px][256rk] f32 (all 64KB, overwrites XT after barrier)
//   phase 2: PL[px][256eg] f16 aliased into MT row px's first 512B
//            (row-private: only the 4 threads of px touch it, reads first)
// ---------------------------------------------------------------------------
template<bool F16Y>
__global__ __launch_bounds__(256, 2) void compute_y(
        const float* __restrict__ x, const _Float16* __restrict__ W1p,
        const _Float16* __restrict__ W2p, float* __restrict__ y,
        _Float16* __restrict__ y16, float* __restrict__ ssum,
        float* __restrict__ ssq) {
    __shared__ __align__(16) float S[16384];      // 64KB
    _Float16* XT  = (_Float16*)S;                 // f16 view (staging)
    float*    Mf  = S;                            // f32 view (MT)
    _Float16* PLb = (_Float16*)S;                 // f16 view (PL overlay)

    const int t = threadIdx.x;
    const int l = t & 63, w = t >> 6;
    const int a = blockIdx.x >> 6;
    const int pixbase = (blockIdx.x & 63) * 64;
    const int row16 = l & 15, kg = l >> 4;
    const float* xa = x + (size_t)a * NC * HW + pixbase;

    // ---- cooperative x load -> XT[px][c] f16 (16B-unit XOR swizzle) ----
    {
        const int px = t & 63;
        const int o0 = t >> 6;                    // 0..3
#pragma unroll
        for (int q = 0; q < 8; ++q) {
            const int oct = q * 4 + o0;           // 0..31
            half8_t hv;
#pragma unroll
            for (int j = 0; j < 8; ++j)
                hv[j] = (_Float16)xa[(size_t)(oct * 8 + j) * HW + px];
            *(half8_t*)&XT[px * 256 + ((oct ^ (px & 15)) << 3)] = hv;
        }
    }
    __syncthreads();                                    // (1)

    // ---- stage A: M = W1T . x  (rolling weight prefetch; acc stays f32) ----
    floatx4 acc[4][4];
#pragma unroll
    for (int i = 0; i < 4; ++i)
#pragma unroll
        for (int j = 0; j < 4; ++j) acc[i][j] = (floatx4){0.f, 0.f, 0.f, 0.f};
    {
        const half8_t* W1v = (const half8_t*)W1p;
        half8_t af[4], afn[4];
#pragma unroll
        for (int rq = 0; rq < 4; ++rq) af[rq] = W1v[(w * 4 + rq) * 64 + l];
        for (int ks = 0; ks < 8; ++ks) {
            if (ks < 7) {
#pragma unroll
                for (int rq = 0; rq < 4; ++rq)
                    afn[rq] = W1v[((ks + 1) * 16 + w * 4 + rq) * 64 + l];
            }
#pragma unroll
            for (int pt = 0; pt < 4; ++pt) {
                const int px = pt * 16 + row16;
                half8_t bf = *(const half8_t*)
                    &XT[px * 256 + (((ks * 4 + kg) ^ row16) << 3)];
#pragma unroll
                for (int rq = 0; rq < 4; ++rq)
                    acc[rq][pt] = __builtin_amdgcn_mfma_f32_16x16x32_f16(
                                      af[rq], bf, acc[rq][pt], 0, 0, 0);
            }
#pragma unroll
            for (int rq = 0; rq < 4; ++rq) af[rq] = afn[rq];
        }
    }

    // ---- prefetch stage-C ks=0 weight fragments (fly under B) ----
    const half8_t* W2v = (const half8_t*)W2p;
    half8_t caf[4], cafn[4];
#pragma unroll
    for (int dq = 0; dq < 4; ++dq) caf[dq] = W2v[(w * 4 + dq) * 64 + l];

    __syncthreads();                                    // (2a) XT dead

    // ---- MT write (f32, float4-unit XOR swizzle) ----
#pragma unroll
    for (int rq = 0; rq < 4; ++rq) {
        const int u = (w * 4 + rq) * 4 + kg;            // float4 unit 0..63
#pragma unroll
        for (int pt = 0; pt < 4; ++pt) {
            const int px = pt * 16 + row16;
            *(floatx4*)&Mf[px * 256 + ((u ^ row16) << 2)] = acc[rq][pt];
        }
    }
    __syncthreads();                                    // (2b)

    // ---- stage B: per-pixel P = M*M, all-f32 reads (no unpack) ----
    {
        const int p = t >> 2, qe = t & 3, ps = p & 15;
        const float* Mp = &Mf[p * 256];
        float Af[4][16];
#pragma unroll
        for (int i = 0; i < 4; ++i) {
            const int e = i * 4 + qe;
#pragma unroll
            for (int f4 = 0; f4 < 4; ++f4) {
                floatx4 v = *(const floatx4*)&Mp[(((e * 4 + f4) ^ ps) << 2)];
#pragma unroll
                for (int j = 0; j < 4; ++j) Af[i][f4 * 4 + j] = v[j];
            }
        }
        floatx2 Pacc[4][8];
#pragma unroll
        for (int i = 0; i < 4; ++i)
#pragma unroll
            for (int g2 = 0; g2 < 8; ++g2) Pacc[i][g2] = (floatx2){0.f, 0.f};
#pragma unroll
        for (int f = 0; f < 16; ++f) {
            floatx2 Bg[8];
#pragma unroll
            for (int g4 = 0; g4 < 4; ++g4) {
                floatx4 v = *(const floatx4*)&Mp[(((f * 4 + g4) ^ ps) << 2)];
                Bg[g4 * 2]     = (floatx2){v[0], v[1]};
                Bg[g4 * 2 + 1] = (floatx2){v[2], v[3]};
            }
#pragma unroll
            for (int i = 0; i < 4; ++i) {
                floatx2 a2 = {Af[i][f], Af[i][f]};
#pragma unroll
                for (int g2 = 0; g2 < 8; ++g2)
                    Pacc[i][g2] = __builtin_elementwise_fma(a2, Bg[g2], Pacc[i][g2]);
            }
        }
        // PL[px][eg] f16 via v_cvt_pkrtz (half8 units, XOR swizzle), aliased
        // into MT row p's first 512B — all Mp reads above are done.
#pragma unroll
        for (int i = 0; i < 4; ++i) {
            const int e = i * 4 + qe;
#pragma unroll
            for (int h2 = 0; h2 < 2; ++h2) {
                half8_t hv;
#pragma unroll
                for (int g2 = 0; g2 < 4; ++g2) {
                    fp16x2 pk = __builtin_amdgcn_cvt_pkrtz(
                        Pacc[i][h2 * 4 + g2][0], Pacc[i][h2 * 4 + g2][1]);
                    hv[g2 * 2]     = (_Float16)pk[0];
                    hv[g2 * 2 + 1] = (_Float16)pk[1];
                }
                *(half8_t*)&PLb[p * 512 + (((e * 2 + h2) ^ ps) << 3)] = hv;
            }
        }
    }
    __syncthreads();                                    // (3)

    // ---- stage C: yT = W2T . P  (rolling weight prefetch) ----
    floatx4 cacc[4][4];
#pragma unroll
    for (int i = 0; i < 4; ++i)
#pragma unroll
        for (int j = 0; j < 4; ++j) cacc[i][j] = (floatx4){0.f, 0.f, 0.f, 0.f};
    for (int ks = 0; ks < 8; ++ks) {
        if (ks < 7) {
#pragma unroll
            for (int dq = 0; dq < 4; ++dq)
                cafn[dq] = W2v[((ks + 1) * 16 + w * 4 + dq) * 64 + l];
        }
#pragma unroll
        for (int pt = 0; pt < 4; ++pt) {
            const int px = pt * 16 + row16;
            half8_t bf = *(const half8_t*)
                &PLb[px * 512 + (((ks * 4 + kg) ^ row16) << 3)];
#pragma unroll
            for (int dq = 0; dq < 4; ++dq)
                cacc[dq][pt] = __builtin_amdgcn_mfma_f32_16x16x32_f16(
                                   caf[dq], bf, cacc[dq][pt], 0, 0, 0);
        }
#pragma unroll
        for (int dq = 0; dq < 4; ++dq) caf[dq] = cafn[dq];
    }

    // ---- epilogue: stores (f16 scaled or f32) + shuffle-reduced stats ----
    float*     ya   = y   + (size_t)a * ND * HW + pixbase;
    _Float16*  ya16 = F16Y ? (y16 + (size_t)a * ND * HW + pixbase) : nullptr;
#pragma unroll
    for (int dq = 0; dq < 4; ++dq) {
        const int dbase = (w * 4 + dq) * 16 + kg * 4;
#pragma unroll
        for (int r2 = 0; r2 < 4; ++r2) {
            const int d = dbase + r2;
            float s = 0.f, q2 = 0.f;
#pragma unroll
            for (int pt = 0; pt < 4; ++pt) {
                float v;
                if (F16Y) {
                    _Float16 hv = (_Float16)cacc[dq][pt][r2];   // ys = 4096*y
                    ya16[(size_t)d * HW + pt * 16 + row16] = hv;
                    v = (float)hv;
                } else {
                    v = cacc[dq][pt][r2] * INV_MSCALE2;
                    ya[(size_t)d * HW + pt * 16 + row16] = v;
                }
                s += v; q2 += v * v;
            }
#pragma unroll
            for (int off = 1; off < 16; off <<= 1) {
                s  += __shfl_xor(s, off);
                q2 += __shfl_xor(q2, off);
            }
            if (row16 == 0) {
                atomicAdd(&ssum[a * 256 + d], s);
                atomicAdd(&ssq [a * 256 + d], q2);
            }
        }
    }
}

// ---------------------------------------------------------------------------
// finalize (f16 path): one block per (a,d); stats computed inline
// ---------------------------------------------------------------------------
__global__ __launch_bounds__(256) void finalize_f16(
        const _Float16* __restrict__ y16, const float* __restrict__ ssum,
        const float* __restrict__ ssq, float* __restrict__ out) {
    const int ad = blockIdx.x;
    const float m  = ssum[ad] * (1.f / HW);
    const float sv = ssq[ad] * (1.f / HW) - m * m;
    const float s  = rsqrtf(sv + EPS_SCALED);
    const size_t base = (size_t)ad * HW + threadIdx.x * 16;
    half8_t h0 = *(const half8_t*)&y16[base];
    half8_t h1 = *(const half8_t*)&y16[base + 8];
    float o[16];
#pragma unroll
    for (int j = 0; j < 8; ++j) {
        float z0 = ((float)h0[j] - m) * s;
        float z1 = ((float)h1[j] - m) * s;
        o[j]     = z0 / (1.f + fabsf(z0));
        o[8 + j] = z1 / (1.f + fabsf(z1));
    }
#pragma unroll
    for (int q = 0; q < 4; ++q)
        *(float4*)&out[base + q * 4] =
            make_float4(o[q * 4], o[q * 4 + 1], o[q * 4 + 2], o[q * 4 + 3]);
}

// ---------------------------------------------------------------------------
// finalize (f32 fallback): in-place on d_out, inline stats
// ---------------------------------------------------------------------------
__global__ __launch_bounds__(256) void finalize_f32(
        float* __restrict__ y, const float* __restrict__ ssum,
        const float* __restrict__ ssq) {
    const int i4 = blockIdx.x * 256 + threadIdx.x;
    const int ad = i4 >> 10;
    const float m  = ssum[ad] * (1.f / HW);
    const float sv = ssq[ad] * (1.f / HW) - m * m;
    const float s  = rsqrtf(sv + 1e-5f);
    float4 v = ((const float4*)y)[i4];
    float vv[4] = {v.x, v.y, v.z, v.w};
#pragma unroll
    for (int lq = 0; lq < 4; ++lq) {
        float z = (vv[lq] - m) * s;
        vv[lq] = z / (1.f + fabsf(z));
    }
    ((float4*)y)[i4] = make_float4(vv[0], vv[1], vv[2], vv[3]);
}

// ---------------------------------------------------------------------------
extern "C" void kernel_launch(void* const* d_in, const int* in_sizes, int n_in,
                              void* d_out, int out_size, void* d_ws, size_t ws_size,
                              hipStream_t stream) {
    const float* x      = (const float*)d_in[0];
    const float* w_core = (const float*)d_in[1];
    const float* w_out  = (const float*)d_in[2];
    float* y = (float*)d_out;

    char* wsb = (char*)d_ws;
    _Float16* W1p = (_Float16*)wsb;                       // 128KB
    _Float16* W2p = (_Float16*)(wsb + 131072);            // 128KB
    float* ssum   = (float*)(wsb + 262144);               // 16KB
    float* ssq    = (float*)(wsb + 278528);               // 16KB
    _Float16* y16 = (_Float16*)(wsb + 294912);            // 32MB (f16 path)

    const size_t need_f16 = 294912 + (size_t)NB * ND * HW * sizeof(_Float16);
    const bool use_f16 = ws_size >= need_f16;

    prep_weights<<<64, 256, 0, stream>>>(w_core, w_out, W1p, W2p, ssum);
    if (use_f16) {
        compute_y<true><<<1024, 256, 0, stream>>>(x, W1p, W2p, y, y16, ssum, ssq);
        finalize_f16<<<4096, 256, 0, stream>>>(y16, ssum, ssq, y);
    } else {
        compute_y<false><<<1024, 256, 0, stream>>>(x, W1p, W2p, y, nullptr, ssum, ssq);
        finalize_f32<<<16384, 256, 0, stream>>>(y, ssum, ssq);
    }
}

// Round 9
// 81.263 us; speedup vs baseline: 1.2391x; 1.0152x over previous
//
#include <hip/hip_runtime.h>

#define HW 4096      // 64*64 pixels per image
#define NC 256       // C_in
#define ND 256       // C_out
#define NB 16        // batch

typedef _Float16 half2_t __attribute__((ext_vector_type(2)));
typedef _Float16 half4_t __attribute__((ext_vector_type(4)));
typedef _Float16 half8_t __attribute__((ext_vector_type(8)));
typedef __fp16   fp16x2  __attribute__((ext_vector_type(2)));
typedef float floatx2 __attribute__((ext_vector_type(2)));
typedef float floatx4 __attribute__((ext_vector_type(4)));

#define MSCALE 64.0f                 // M scaled by 2^6 -> P,y scaled by 2^12
#define INV_MSCALE2 (1.0f / 4096.0f)
#define EPS_SCALED (1e-5f * 4096.0f * 4096.0f)   // eps for scaled-y stats

// ---------------------------------------------------------------------------
// prep: pack A-operand fragment streams, K-chunk-major:
//   addr = ((ks*16 + rt)*64 + l)*8 + j
// Also zeroes ssum/ssq (replaces a memset launch).
// ---------------------------------------------------------------------------
__global__ __launch_bounds__(256) void prep_weights(
        const float* __restrict__ w_core, const float* __restrict__ w_out,
        _Float16* __restrict__ W1p, _Float16* __restrict__ W2p,
        float* __restrict__ ssum) {
    int tid = blockIdx.x * 256 + threadIdx.x;   // 16384 threads
    if (tid < 8192) ssum[tid] = 0.f;            // ssum+ssq contiguous
    int l   = tid & 63;
    int rt  = (tid >> 6) & 15;
    int ks  = (tid >> 10) & 7;
    int sel = tid >> 13;
    int row = l & 15, kg = l >> 4;
    half8_t v;
    if (sel == 0) {
        int r = rt, k = row;
#pragma unroll
        for (int j = 0; j < 8; ++j) {
            int c = ks * 32 + kg * 8 + j;
            v[j] = (_Float16)(w_core[r * 4096 + c * 16 + k] * MSCALE);
        }
        *(half8_t*)&W1p[(size_t)((ks * 16 + rt) * 64 + l) * 8] = v;
    } else {
        int d = rt * 16 + row;
#pragma unroll
        for (int j = 0; j < 8; ++j) {
            int eg = ks * 32 + kg * 8 + j, e = eg >> 4, g = eg & 15;
            v[j] = (_Float16)w_out[g * 4096 + d * 16 + e];
        }
        *(half8_t*)&W2p[(size_t)((ks * 16 + rt) * 64 + l) * 8] = v;
    }
}

// ---------------------------------------------------------------------------
// Fused: M = W1T.x -> P = M*M -> yT = W2T.P, + partial instance-norm stats.
// 64 px/block, 4 waves; wave owns rt/dt {4w..4w+3} x all 4 pixel tiles.
// SINGLE 32KB LDS region S, phase-reused (targets 4 blocks/CU):
//   phase 0: XT[64px][256c]  f16 swz   (x staging / stage-A B-fragments)
//   phase 1: MT[64px][256rk] f16 swz   (overlay after barrier 2a)
//   phase 2: PL[64px][256eg] f16 swz   (overwrites MT row px in stage B;
//            wave-lockstep-safe: all of a wave's reads precede its writes,
//            and row px is touched only by the wave owning px in stage B)
// ---------------------------------------------------------------------------
template<bool F16Y>
__global__ __launch_bounds__(256, 2) void compute_y(
        const float* __restrict__ x, const _Float16* __restrict__ W1p,
        const _Float16* __restrict__ W2p, float* __restrict__ y,
        _Float16* __restrict__ y16, float* __restrict__ ssum,
        float* __restrict__ ssq) {
    __shared__ __align__(16) _Float16 S[16384];   // 32KB

    const int t = threadIdx.x;
    const int l = t & 63, w = t >> 6;
    const int a = blockIdx.x >> 6;
    const int pixbase = (blockIdx.x & 63) * 64;
    const int row16 = l & 15, kg = l >> 4;
    const float* xa = x + (size_t)a * NC * HW + pixbase;

    // ---- W1 ks=0 fragments issued first (in flight during x staging) ----
    const half8_t* W1v = (const half8_t*)W1p;
    half8_t af[4], afn[4];
#pragma unroll
    for (int rq = 0; rq < 4; ++rq) af[rq] = W1v[(w * 4 + rq) * 64 + l];

    // ---- x staging -> XT f16, 32-outstanding load batches ----
    {
        const int px = t & 63;
        const int o0 = t >> 6;                    // wave-uniform
#pragma unroll
        for (int h = 0; h < 2; ++h) {
            float xr[32];
#pragma unroll
            for (int q = 0; q < 4; ++q) {
                const int oct = (h * 4 + q) * 4 + o0;
#pragma unroll
                for (int j = 0; j < 8; ++j)
                    xr[q * 8 + j] = xa[(size_t)(oct * 8 + j) * HW + px];
            }
#pragma unroll
            for (int q = 0; q < 4; ++q) {
                const int oct = (h * 4 + q) * 4 + o0;
                half8_t hv;
#pragma unroll
                for (int j = 0; j < 8; ++j) hv[j] = (_Float16)xr[q * 8 + j];
                *(half8_t*)&S[px * 256 + ((oct ^ (px & 15)) << 3)] = hv;
            }
        }
    }
    __syncthreads();                                    // (1)

    // ---- stage A: M = W1T . x  (rolling weight prefetch) ----
    floatx4 acc[4][4];
#pragma unroll
    for (int i = 0; i < 4; ++i)
#pragma unroll
        for (int j = 0; j < 4; ++j) acc[i][j] = (floatx4){0.f, 0.f, 0.f, 0.f};
    for (int ks = 0; ks < 8; ++ks) {
        if (ks < 7) {
#pragma unroll
            for (int rq = 0; rq < 4; ++rq)
                afn[rq] = W1v[((ks + 1) * 16 + w * 4 + rq) * 64 + l];
        }
#pragma unroll
        for (int pt = 0; pt < 4; ++pt) {
            const int px = pt * 16 + row16;
            half8_t bf = *(const half8_t*)
                &S[px * 256 + (((ks * 4 + kg) ^ row16) << 3)];
#pragma unroll
            for (int rq = 0; rq < 4; ++rq)
                acc[rq][pt] = __builtin_amdgcn_mfma_f32_16x16x32_f16(
                                  af[rq], bf, acc[rq][pt], 0, 0, 0);
        }
#pragma unroll
        for (int rq = 0; rq < 4; ++rq) af[rq] = afn[rq];
    }

    // ---- prefetch stage-C ks=0 weight fragments (fly under MT + stage B) ----
    const half8_t* W2v = (const half8_t*)W2p;
    half8_t caf[4], cafn[4];
#pragma unroll
    for (int dq = 0; dq < 4; ++dq) caf[dq] = W2v[(w * 4 + dq) * 64 + l];

    __syncthreads();                                    // (2a) XT dead

    // ---- MT write (f16, half4-unit XOR swizzle) ----
#pragma unroll
    for (int rq = 0; rq < 4; ++rq) {
        const int u = (w * 4 + rq) * 4 + kg;            // half4 unit 0..63
#pragma unroll
        for (int pt = 0; pt < 4; ++pt) {
            const int px = pt * 16 + row16;
            half4_t hv;
#pragma unroll
            for (int r2 = 0; r2 < 4; ++r2) hv[r2] = (_Float16)acc[rq][pt][r2];
            *(half4_t*)&S[px * 256 + ((u ^ row16) << 2)] = hv;
        }
    }
    __syncthreads();                                    // (2b)

    // ---- stage B: per-pixel P = M*M (4 threads/pixel), f4-blocked ----
    {
        const int p = t >> 2, qe = t & 3, ps = p & 15;
        const _Float16* Mp = &S[p * 256];
        floatx2 Pacc[4][8];
#pragma unroll
        for (int i = 0; i < 4; ++i)
#pragma unroll
            for (int g2 = 0; g2 < 8; ++g2) Pacc[i][g2] = (floatx2){0.f, 0.f};
#pragma unroll
        for (int f4 = 0; f4 < 4; ++f4) {
            float Afb[4][4];
#pragma unroll
            for (int i = 0; i < 4; ++i) {
                const int e = i * 4 + qe;
                half4_t v = *(const half4_t*)
                    &Mp[(((e * 4 + f4) ^ ps) << 2)];
#pragma unroll
                for (int j = 0; j < 4; ++j) Afb[i][j] = (float)v[j];
            }
#pragma unroll
            for (int fl = 0; fl < 4; ++fl) {
                const int f = f4 * 4 + fl;
                floatx2 Bg[8];
#pragma unroll
                for (int g4 = 0; g4 < 4; ++g4) {
                    half4_t v = *(const half4_t*)
                        &Mp[(((f * 4 + g4) ^ ps) << 2)];   // broadcast across qe
                    Bg[g4 * 2]     = (floatx2){(float)v[0], (float)v[1]};
                    Bg[g4 * 2 + 1] = (floatx2){(float)v[2], (float)v[3]};
                }
#pragma unroll
                for (int i = 0; i < 4; ++i) {
                    floatx2 a2 = {Afb[i][fl], Afb[i][fl]};
#pragma unroll
                    for (int g2 = 0; g2 < 8; ++g2)
                        Pacc[i][g2] = __builtin_elementwise_fma(a2, Bg[g2],
                                                                Pacc[i][g2]);
                }
            }
        }
        // PL write (overwrites MT row p; all reads above complete first —
        // lockstep within the owning wave)
#pragma unroll
        for (int i = 0; i < 4; ++i) {
            const int e = i * 4 + qe;
#pragma unroll
            for (int h2 = 0; h2 < 2; ++h2) {
                half8_t hv;
#pragma unroll
                for (int g2 = 0; g2 < 4; ++g2) {
                    fp16x2 pk = __builtin_amdgcn_cvt_pkrtz(
                        Pacc[i][h2 * 4 + g2][0], Pacc[i][h2 * 4 + g2][1]);
                    hv[g2 * 2]     = (_Float16)pk[0];
                    hv[g2 * 2 + 1] = (_Float16)pk[1];
                }
                *(half8_t*)&S[p * 256 + (((e * 2 + h2) ^ ps) << 3)] = hv;
            }
        }
    }
    __syncthreads();                                    // (3)

    // ---- stage C: yT = W2T . P  (rolling weight prefetch) ----
    floatx4 cacc[4][4];
#pragma unroll
    for (int i = 0; i < 4; ++i)
#pragma unroll
        for (int j = 0; j < 4; ++j) cacc[i][j] = (floatx4){0.f, 0.f, 0.f, 0.f};
    for (int ks = 0; ks < 8; ++ks) {
        if (ks < 7) {
#pragma unroll
            for (int dq = 0; dq < 4; ++dq)
                cafn[dq] = W2v[((ks + 1) * 16 + w * 4 + dq) * 64 + l];
        }
#pragma unroll
        for (int pt = 0; pt < 4; ++pt) {
            const int px = pt * 16 + row16;
            half8_t bf = *(const half8_t*)
                &S[px * 256 + (((ks * 4 + kg) ^ row16) << 3)];
#pragma unroll
            for (int dq = 0; dq < 4; ++dq)
                cacc[dq][pt] = __builtin_amdgcn_mfma_f32_16x16x32_f16(
                                   caf[dq], bf, cacc[dq][pt], 0, 0, 0);
        }
#pragma unroll
        for (int dq = 0; dq < 4; ++dq) caf[dq] = cafn[dq];
    }

    // ---- epilogue: stores (f16 scaled or f32) + shuffle-reduced stats ----
    float*     ya   = y   + (size_t)a * ND * HW + pixbase;
    _Float16*  ya16 = F16Y ? (y16 + (size_t)a * ND * HW + pixbase) : nullptr;
#pragma unroll
    for (int dq = 0; dq < 4; ++dq) {
        const int dbase = (w * 4 + dq) * 16 + kg * 4;
#pragma unroll
        for (int r2 = 0; r2 < 4; ++r2) {
            const int d = dbase + r2;
            float s = 0.f, q2 = 0.f;
#pragma unroll
            for (int pt = 0; pt < 4; ++pt) {
                float v;
                if (F16Y) {
                    _Float16 hv = (_Float16)cacc[dq][pt][r2];   // ys = 4096*y
                    ya16[(size_t)d * HW + pt * 16 + row16] = hv;
                    v = (float)hv;
                } else {
                    v = cacc[dq][pt][r2] * INV_MSCALE2;
                    ya[(size_t)d * HW + pt * 16 + row16] = v;
                }
                s += v; q2 += v * v;
            }
#pragma unroll
            for (int off = 1; off < 16; off <<= 1) {
                s  += __shfl_xor(s, off);
                q2 += __shfl_xor(q2, off);
            }
            if (row16 == 0) {
                atomicAdd(&ssum[a * 256 + d], s);
                atomicAdd(&ssq [a * 256 + d], q2);
            }
        }
    }
}

// ---------------------------------------------------------------------------
// finalize (f16 path): one block per (a,d); stats computed inline
// ---------------------------------------------------------------------------
__global__ __launch_bounds__(256) void finalize_f16(
        const _Float16* __restrict__ y16, const float* __restrict__ ssum,
        const float* __restrict__ ssq, float* __restrict__ out) {
    const int ad = blockIdx.x;
    const float m  = ssum[ad] * (1.f / HW);
    const float sv = ssq[ad] * (1.f / HW) - m * m;
    const float s  = rsqrtf(sv + EPS_SCALED);
    const size_t base = (size_t)ad * HW + threadIdx.x * 16;
    half8_t h0 = *(const half8_t*)&y16[base];
    half8_t h1 = *(const half8_t*)&y16[base + 8];
    float o[16];
#pragma unroll
    for (int j = 0; j < 8; ++j) {
        float z0 = ((float)h0[j] - m) * s;
        float z1 = ((float)h1[j] - m) * s;
        o[j]     = z0 / (1.f + fabsf(z0));
        o[8 + j] = z1 / (1.f + fabsf(z1));
    }
#pragma unroll
    for (int q = 0; q < 4; ++q)
        *(float4*)&out[base + q * 4] =
            make_float4(o[q * 4], o[q * 4 + 1], o[q * 4 + 2], o[q * 4 + 3]);
}

// ---------------------------------------------------------------------------
// finalize (f32 fallback): in-place on d_out, inline stats
// ---------------------------------------------------------------------------
__global__ __launch_bounds__(256) void finalize_f32(
        float* __restrict__ y, const float* __restrict__ ssum,
        const float* __restrict__ ssq) {
    const int i4 = blockIdx.x * 256 + threadIdx.x;
    const int ad = i4 >> 10;
    const float m  = ssum[ad] * (1.f / HW);
    const float sv = ssq[ad] * (1.f / HW) - m * m;
    const float s  = rsqrtf(sv + 1e-5f);
    float4 v = ((const float4*)y)[i4];
    float vv[4] = {v.x, v.y, v.z, v.w};
#pragma unroll
    for (int lq = 0; lq < 4; ++lq) {
        float z = (vv[lq] - m) * s;
        vv[lq] = z / (1.f + fabsf(z));
    }
    ((float4*)y)[i4] = make_float4(vv[0], vv[1], vv[2], vv[3]);
}

// ---------------------------------------------------------------------------
extern "C" void kernel_launch(void* const* d_in, const int* in_sizes, int n_in,
                              void* d_out, int out_size, void* d_ws, size_t ws_size,
                              hipStream_t stream) {
    const float* x      = (const float*)d_in[0];
    const float* w_core = (const float*)d_in[1];
    const float* w_out  = (const float*)d_in[2];
    float* y = (float*)d_out;

    char* wsb = (char*)d_ws;
    _Float16* W1p = (_Float16*)wsb;                       // 128KB
    _Float16* W2p = (_Float16*)(wsb + 131072);            // 128KB
    float* ssum   = (float*)(wsb + 262144);               // 16KB
    float* ssq    = (float*)(wsb + 278528);               // 16KB
    _Float16* y16 = (_Float16*)(wsb + 294912);            // 32MB (f16 path)

    const size_t need_f16 = 294912 + (size_t)NB * ND * HW * sizeof(_Float16);
    const bool use_f16 = ws_size >= need_f16;

    prep_weights<<<64, 256, 0, stream>>>(w_core, w_out, W1p, W2p, ssum);
    if (use_f16) {
        compute_y<true><<<1024, 256, 0, stream>>>(x, W1p, W2p, y, y16, ssum, ssq);
        finalize_f16<<<4096, 256, 0, stream>>>(y16, ssum, ssq, y);
    } else {
        compute_y<false><<<1024, 256, 0, stream>>>(x, W1p, W2p, y, nullptr, ssum, ssq);
        finalize_f32<<<16384, 256, 0, stream>>>(y, ssum, ssq);
    }
}